// Round 20
// baseline (423.088 us; speedup 1.0000x reference)
//
#include <hip/hip_runtime.h>
#include <hip/hip_bf16.h>

// Problem constants
#define PP 1568
#define TT 8
#define DD 196
#define HD 64
#define NBH 48
#define NROW (NBH*PP*TT)        // 602112 rows per tensor
#define RPW 32                  // rows per wave
#define WPB 2                   // independent waves per block (no barriers)
#define NWAVE (NROW/RPW)        // 18816 waves total
#define NBLK5 (NWAVE/WPB)       // 9408 blocks (selection / fallback)
#define NXCD 8
#define CPX (NBLK5/NXCD)        // 1176
#define WPBP 4                  // waves per block, product kernel
#define NBLK6 (NWAVE/WPBP)      // 4704 blocks (product)
#define CPX6 (NBLK6/NXCD)       // 588
#define NPART NWAVE             // 18816 partials
#define NRED1 ((NPART+255)/256) // 74
#define SUB (8*DD*4)            // 6272 B sub-slab (8 rows)
#define VSLAB (DD*TT*HD)        // floats per (b,h) v slab
#define WPBH 392                // waves per bh (12544 rows / 32)
#define KMASK 0xFFFFFF00u
#define NEG_INF (-3.0e38f)
#define WQ_OFF 80000            // byte offset of wq in d_ws (past partial+p2)
#define ROWB 80                 // bytes of packed (w|idx) per row

typedef float f4 __attribute__((ext_vector_type(4)));
typedef unsigned u4v __attribute__((ext_vector_type(4)));
typedef unsigned u2v __attribute__((ext_vector_type(2)));

__device__ __forceinline__ float readlane_f(float v, int l) {
    return __int_as_float(__builtin_amdgcn_readlane(__float_as_int(v), l));
}

__device__ __forceinline__ float wave_sum_u(float v) {
#define STEPS(ctrl) { float t_ = __int_as_float(__builtin_amdgcn_update_dpp( \
        0, __float_as_int(v), ctrl, 0xF, 0xF, true)); v += t_; }
    STEPS(0x111) STEPS(0x112) STEPS(0x114) STEPS(0x118) STEPS(0x142) STEPS(0x143)
#undef STEPS
    return readlane_f(v, 63);
}

// value part of a packed key (low 8 mantissa bits = idx, zeroed)
__device__ __forceinline__ float kval(float k) {
    return __uint_as_float(__float_as_uint(k) & KMASK);
}

// async HBM -> LDS, 16B per lane (R18-proven)
__device__ __forceinline__ void gload_lds(const void* g, void* l) {
    __builtin_amdgcn_global_load_lds(
        (const __attribute__((address_space(1))) unsigned*)g,
        (__attribute__((address_space(3))) unsigned*)l, 16, 0, 0);
}

// Named members, NOT arrays (R5: arrays -> LDS; R4: refs -> scratch).
// FLOAT keys (R17-proven).
struct K6  { float k0,k1,k2,k3,k4,k5; };
struct K10 { float k0,k1,k2,k3,k4,k5,k6,k7,k8,k9; };
struct MR  { K10 f; float mx; };

// med3 sorted-insert (R13-proven), depth-6 (R10-proven).
#define PUTK6(Q,X,D) { \
  unsigned cu_=(__float_as_uint(X)&KMASK)|(unsigned)(D); \
  float c_=__uint_as_float(cu_); \
  float n0_=fmaxf(Q.k0,c_); \
  float n1_=__builtin_amdgcn_fmed3f(Q.k0,Q.k1,c_); \
  float n2_=__builtin_amdgcn_fmed3f(Q.k1,Q.k2,c_); \
  float n3_=__builtin_amdgcn_fmed3f(Q.k2,Q.k3,c_); \
  float n4_=__builtin_amdgcn_fmed3f(Q.k3,Q.k4,c_); \
  float n5_=__builtin_amdgcn_fmed3f(Q.k4,Q.k5,c_); \
  Q.k0=n0_; Q.k1=n1_; Q.k2=n2_; Q.k3=n3_; Q.k4=n4_; Q.k5=n5_; }
#define PUT4K6(Q,V,D0) PUTK6(Q,(V).x,(D0)) PUTK6(Q,(V).y,(D0)+1) \
                       PUTK6(Q,(V).z,(D0)+2) PUTK6(Q,(V).w,(D0)+3)

// lane's chain over its eighth of row a (LDS staging — the only fetch-clean
// pattern; per-lane global streaming measured 1.75-1.89GB in R11/R14/R15)
__device__ __forceinline__ K6 chain_rows(const char* stg, int a, int b8) {
    K6 q = {NEG_INF,NEG_INF,NEG_INF,NEG_INF,NEG_INF,NEG_INF};
    const char* rb = stg + a*784 + b8*16;
    f4 v;
    v = *(const f4*)(rb);       PUT4K6(q, v, b8*4)
    v = *(const f4*)(rb+128);   PUT4K6(q, v, b8*4+32)
    v = *(const f4*)(rb+256);   PUT4K6(q, v, b8*4+64)
    v = *(const f4*)(rb+384);   PUT4K6(q, v, b8*4+96)
    v = *(const f4*)(rb+512);   PUT4K6(q, v, b8*4+128)
    v = *(const f4*)(rb+640);   PUT4K6(q, v, b8*4+160)
    if (b8 == 7) { f4 w = *(const f4*)(stg + a*784 + 768); PUT4K6(q, w, 192) }
    return q;
}

#define FSWZ(x, pat) __int_as_float(__builtin_amdgcn_ds_swizzle(__float_as_int(x), pat))
__device__ __forceinline__ K6 kshuf8_6(K6 a) {
    K6 r;
    r.k0=FSWZ(a.k0,0x201F); r.k1=FSWZ(a.k1,0x201F); r.k2=FSWZ(a.k2,0x201F);
    r.k3=FSWZ(a.k3,0x201F); r.k4=FSWZ(a.k4,0x201F); r.k5=FSWZ(a.k5,0x201F);
    return r;
}
__device__ __forceinline__ K10 kshuf16(K10 a) {
    K10 r;
    r.k0=FSWZ(a.k0,0x401F); r.k1=FSWZ(a.k1,0x401F); r.k2=FSWZ(a.k2,0x401F);
    r.k3=FSWZ(a.k3,0x401F); r.k4=FSWZ(a.k4,0x401F); r.k5=FSWZ(a.k5,0x401F);
    r.k6=FSWZ(a.k6,0x401F); r.k7=FSWZ(a.k7,0x401F); r.k8=FSWZ(a.k8,0x401F);
    r.k9=FSWZ(a.k9,0x401F);
    return r;
}
__device__ __forceinline__ float fbp(int bpx, float x) {
    return __int_as_float(__builtin_amdgcn_ds_bpermute(bpx, __float_as_int(x)));
}
__device__ __forceinline__ K10 kbp32(K10 a, int bpx) {
    K10 r;
    r.k0=fbp(bpx,a.k0); r.k1=fbp(bpx,a.k1); r.k2=fbp(bpx,a.k2);
    r.k3=fbp(bpx,a.k3); r.k4=fbp(bpx,a.k4); r.k5=fbp(bpx,a.k5);
    r.k6=fbp(bpx,a.k6); r.k7=fbp(bpx,a.k7); r.k8=fbp(bpx,a.k8);
    r.k9=fbp(bpx,a.k9);
    return r;
}

// merge two sorted-desc 6-lists -> sorted-desc top-10 of the 12-union.
__device__ __forceinline__ K10 kmrg66(K6 A, K6 B) {
    float p00=fminf(A.k0,B.k0);
    float p01=fminf(A.k0,B.k1), p10=fminf(A.k1,B.k0);
    float p02=fminf(A.k0,B.k2), p11=fminf(A.k1,B.k1), p20=fminf(A.k2,B.k0);
    float p03=fminf(A.k0,B.k3), p12=fminf(A.k1,B.k2), p21=fminf(A.k2,B.k1), p30=fminf(A.k3,B.k0);
    float p04=fminf(A.k0,B.k4), p13=fminf(A.k1,B.k3), p22=fminf(A.k2,B.k2), p31=fminf(A.k3,B.k1), p40=fminf(A.k4,B.k0);
    float p05=fminf(A.k0,B.k5), p14=fminf(A.k1,B.k4), p23=fminf(A.k2,B.k3), p32=fminf(A.k3,B.k2), p41=fminf(A.k4,B.k1), p50=fminf(A.k5,B.k0);
    float p15=fminf(A.k1,B.k5), p24=fminf(A.k2,B.k4), p33=fminf(A.k3,B.k3), p42=fminf(A.k4,B.k2), p51=fminf(A.k5,B.k1);
    float p25=fminf(A.k2,B.k5), p34=fminf(A.k3,B.k4), p43=fminf(A.k4,B.k3), p52=fminf(A.k5,B.k2);
    float p35=fminf(A.k3,B.k5), p44=fminf(A.k4,B.k4), p53=fminf(A.k5,B.k3);
    K10 M;
    M.k0=fmaxf(A.k0,B.k0);
    M.k1=fmaxf(fmaxf(A.k1,B.k1),p00);
    M.k2=fmaxf(fmaxf(A.k2,B.k2),fmaxf(p01,p10));
    M.k3=fmaxf(fmaxf(A.k3,B.k3),fmaxf(p02,fmaxf(p11,p20)));
    M.k4=fmaxf(fmaxf(A.k4,B.k4),fmaxf(fmaxf(p03,p12),fmaxf(p21,p30)));
    M.k5=fmaxf(fmaxf(A.k5,B.k5),fmaxf(fmaxf(p04,p13),fmaxf(p22,fmaxf(p31,p40))));
    M.k6=fmaxf(fmaxf(p05,p14),fmaxf(fmaxf(p23,p32),fmaxf(p41,p50)));
    M.k7=fmaxf(fmaxf(p15,p24),fmaxf(p33,fmaxf(p42,p51)));
    M.k8=fmaxf(fmaxf(p25,p34),fmaxf(p43,p52));
    M.k9=fmaxf(p35,fmaxf(p44,p53));
    return M;
}

// merge two sorted-desc 10-lists -> sorted-desc top-10 of union.
__device__ __forceinline__ K10 kmrg(K10 A, K10 B) {
    float p00=fminf(A.k0,B.k0);
    float p01=fminf(A.k0,B.k1), p10=fminf(A.k1,B.k0);
    float p02=fminf(A.k0,B.k2), p11=fminf(A.k1,B.k1), p20=fminf(A.k2,B.k0);
    float p03=fminf(A.k0,B.k3), p12=fminf(A.k1,B.k2), p21=fminf(A.k2,B.k1), p30=fminf(A.k3,B.k0);
    float p04=fminf(A.k0,B.k4), p13=fminf(A.k1,B.k3), p22=fminf(A.k2,B.k2), p31=fminf(A.k3,B.k1), p40=fminf(A.k4,B.k0);
    float p05=fminf(A.k0,B.k5), p14=fminf(A.k1,B.k4), p23=fminf(A.k2,B.k3), p32=fminf(A.k3,B.k2), p41=fminf(A.k4,B.k1), p50=fminf(A.k5,B.k0);
    float p06=fminf(A.k0,B.k6), p15=fminf(A.k1,B.k5), p24=fminf(A.k2,B.k4), p33=fminf(A.k3,B.k3), p42=fminf(A.k4,B.k2), p51=fminf(A.k5,B.k1), p60=fminf(A.k6,B.k0);
    float p07=fminf(A.k0,B.k7), p16=fminf(A.k1,B.k6), p25=fminf(A.k2,B.k5), p34=fminf(A.k3,B.k4), p43=fminf(A.k4,B.k3), p52=fminf(A.k5,B.k2), p61=fminf(A.k6,B.k1), p70=fminf(A.k7,B.k0);
    float p08=fminf(A.k0,B.k8), p17=fminf(A.k1,B.k7), p26=fminf(A.k2,B.k6), p35=fminf(A.k3,B.k5), p44=fminf(A.k4,B.k4), p53=fminf(A.k5,B.k3), p62=fminf(A.k6,B.k2), p71=fminf(A.k7,B.k1), p80=fminf(A.k8,B.k0);
    K10 M;
    M.k0=fmaxf(A.k0,B.k0);
    M.k1=fmaxf(fmaxf(A.k1,B.k1),p00);
    M.k2=fmaxf(fmaxf(A.k2,B.k2),fmaxf(p01,p10));
    M.k3=fmaxf(fmaxf(A.k3,B.k3),fmaxf(p02,fmaxf(p11,p20)));
    M.k4=fmaxf(fmaxf(A.k4,B.k4),fmaxf(fmaxf(p03,p12),fmaxf(p21,p30)));
    M.k5=fmaxf(fmaxf(A.k5,B.k5),fmaxf(fmaxf(p04,p13),fmaxf(p22,fmaxf(p31,p40))));
    M.k6=fmaxf(fmaxf(A.k6,B.k6),fmaxf(fmaxf(p05,p14),fmaxf(fmaxf(p23,p32),fmaxf(p41,p50))));
    M.k7=fmaxf(fmaxf(A.k7,B.k7),fmaxf(fmaxf(fmaxf(p06,p15),fmaxf(p24,p33)),fmaxf(fmaxf(p42,p51),p60)));
    M.k8=fmaxf(fmaxf(A.k8,B.k8),fmaxf(fmaxf(fmaxf(p07,p16),fmaxf(p25,p34)),fmaxf(fmaxf(p43,p52),fmaxf(p61,p70))));
    M.k9=fmaxf(fmaxf(A.k9,B.k9),fmaxf(fmaxf(fmaxf(p08,p17),fmaxf(p26,p35)),fmaxf(fmaxf(p44,p53),fmaxf(fmaxf(p62,p71),p80))));
    return M;
}

// eighth-chains -> row top-10 set + row max key
__device__ __forceinline__ MR merge_all(K6 q, int bpx) {
    K10 m = kmrg66(q, kshuf8_6(q));
    K10 n = kmrg(m, kshuf16(m));
    K10 r = kbp32(n, bpx);
    MR out;
    out.mx = fmaxf(n.k0, r.k0);
    out.f.k0=fmaxf(n.k0,r.k9); out.f.k1=fmaxf(n.k1,r.k8); out.f.k2=fmaxf(n.k2,r.k7);
    out.f.k3=fmaxf(n.k3,r.k6); out.f.k4=fmaxf(n.k4,r.k5); out.f.k5=fmaxf(n.k5,r.k4);
    out.f.k6=fmaxf(n.k6,r.k3); out.f.k7=fmaxf(n.k7,r.k2); out.f.k8=fmaxf(n.k8,r.k1);
    out.f.k9=fmaxf(n.k9,r.k0);
    return out;
}

#define STAGE(SRC) { const char* s_=(SRC); \
    gload_lds(s_ +         (size_t)lane*16, stg); \
    gload_lds(s_ + 1024 +  (size_t)lane*16, stg+1024); \
    gload_lds(s_ + 2048 +  (size_t)lane*16, stg+2048); \
    gload_lds(s_ + 3072 +  (size_t)lane*16, stg+3072); \
    gload_lds(s_ + 4096 +  (size_t)lane*16, stg+4096); \
    gload_lds(s_ + 5120 +  (size_t)lane*16, stg+5120); \
    if (lane < 8) gload_lds(s_ + 6144 + (size_t)lane*16, stg+6144); }
#define WAITV asm volatile("s_waitcnt vmcnt(0)" ::: "memory");

// pack (weight,f-idx): weight's low 8 mantissa bits replaced by the d-index
#define PKW(F,K) ((__float_as_uint(F)&KMASK)|(__float_as_uint(K)&0xFFu))

// ======== S-phase / T-phase bodies, shared between split & fallback ========
// S phase: chain+merge+weights, then emit 10 packed u32 (dies immediately)
#define SBODY(EMIT10) { \
    MR mS = merge_all(qS, bpx); \
    K10 fS = mS.f; \
    float CS = kval(mS.mx); \
    float wS0=__expf(kval(fS.k0)-CS), wS1=__expf(kval(fS.k1)-CS), \
          wS2=__expf(kval(fS.k2)-CS), wS3=__expf(kval(fS.k3)-CS), \
          wS4=__expf(kval(fS.k4)-CS), wS5=__expf(kval(fS.k5)-CS), \
          wS6=__expf(kval(fS.k6)-CS), wS7=__expf(kval(fS.k7)-CS), \
          wS8=__expf(kval(fS.k8)-CS), wS9=__expf(kval(fS.k9)-CS); \
    float wsS = (((wS0+wS1)+(wS2+wS3))+((wS4+wS5)+(wS6+wS7)))+(wS8+wS9); \
    float invS = __builtin_amdgcn_rcpf(wsS); \
    if (lane < 8) { EMIT10 } }
#define TBODY(EMIT10) { \
    MR mT = merge_all(qT, bpx); \
    K10 fT = mT.f; \
    float CT = kval(mT.mx); \
    float wT0=__expf(kval(fT.k0)-CT), wT1=__expf(kval(fT.k1)-CT), \
          wT2=__expf(kval(fT.k2)-CT), wT3=__expf(kval(fT.k3)-CT), \
          wT4=__expf(kval(fT.k4)-CT), wT5=__expf(kval(fT.k5)-CT), \
          wT6=__expf(kval(fT.k6)-CT), wT7=__expf(kval(fT.k7)-CT), \
          wT8=__expf(kval(fT.k8)-CT), wT9=__expf(kval(fT.k9)-CT); \
    float wsT = (((wT0+wT1)+(wT2+wT3))+((wT4+wT5)+(wT6+wT7)))+(wT8+wT9); \
    float invT = -__builtin_amdgcn_rcpf(wsT); \
    if (lane < 8) { EMIT10 } }

// ================= SPLIT PATH: selection kernel (LDS = staging only) =======
__global__ __launch_bounds__(128) void vtop_sel(
        const float* __restrict__ att_s, const float* __restrict__ att_t,
        char* __restrict__ wq) {
    __shared__ f4 stgv[WPB][SUB/16];        // 12544 B/block -> 13 blocks/CU

    int tid  = threadIdx.x;
    int wid  = tid >> 6;
    int lane = tid & 63;
    char* stg = (char*)&stgv[wid][0];
    int a = lane & 7, b8 = lane >> 3;
    int bpx = (lane ^ 32) << 2;

    int blk = (blockIdx.x % NXCD) * CPX + blockIdx.x / NXCD;   // R16-proven
    int gwave = blk * WPB + wid;

    const char* baseS = (const char*)att_s + (size_t)gwave * (RPW*DD*4);
    const char* baseT = (const char*)att_t + (size_t)gwave * (RPW*DD*4);
    char* wqw = wq + (size_t)gwave * (RPW*ROWB);

    STAGE(baseS)

#pragma unroll 1
    for (int s = 0; s < 4; ++s) {
        char* rp = wqw + (size_t)((s << 3) | (lane & 7)) * ROWB;
        WAITV
        K6 qS = chain_rows(stg, a, b8);
        STAGE(baseT + s*SUB)
        SBODY(
            u4v w;
            w.x=PKW(wS0*invS,fS.k0); w.y=PKW(wS1*invS,fS.k1);
            w.z=PKW(wS2*invS,fS.k2); w.w=PKW(wS3*invS,fS.k3);
            *(u4v*)(rp) = w;
            w.x=PKW(wS4*invS,fS.k4); w.y=PKW(wS5*invS,fS.k5);
            w.z=PKW(wS6*invS,fS.k6); w.w=PKW(wS7*invS,fS.k7);
            *(u4v*)(rp+16) = w;
            u2v h; h.x=PKW(wS8*invS,fS.k8); h.y=PKW(wS9*invS,fS.k9);
            *(u2v*)(rp+32) = h;
        )
        WAITV
        K6 qT = chain_rows(stg, a, b8);
        if (s < 3) STAGE(baseS + (s+1)*SUB)
        TBODY(
            u2v h; h.x=PKW(wT0*invT,fT.k0); h.y=PKW(wT1*invT,fT.k1);
            *(u2v*)(rp+40) = h;
            u4v w;
            w.x=PKW(wT2*invT,fT.k2); w.y=PKW(wT3*invT,fT.k3);
            w.z=PKW(wT4*invT,fT.k4); w.w=PKW(wT5*invT,fT.k5);
            *(u4v*)(rp+48) = w;
            w.x=PKW(wT6*invT,fT.k6); w.y=PKW(wT7*invT,fT.k7);
            w.z=PKW(wT8*invT,fT.k8); w.w=PKW(wT9*invT,fT.k9);
            *(u4v*)(rp+64) = w;
        )
    }
}

// ================= SPLIT PATH: product kernel (zero LDS, max occupancy) ====
__global__ __launch_bounds__(256) void vtop_prod(
        const float* __restrict__ v_s, const float* __restrict__ v_t,
        const char* __restrict__ wq, float* __restrict__ partial) {
    int tid  = threadIdx.x;
    int wid  = tid >> 6;
    int lane = tid & 63;

    int blk = (blockIdx.x % NXCD) * CPX6 + blockIdx.x / NXCD;
    int gwave = blk * WPBP + wid;
    int bh = gwave / WPBH;

    const u4v* wqw = (const u4v*)(wq + (size_t)gwave * (RPW*ROWB));
    const float* vSb = v_s + (size_t)bh * VSLAB;
    const float* vTb = v_t + (size_t)bh * VSLAB;
    unsigned ul = (unsigned)lane;
    float lacc = 0.f;
#pragma unroll 1
    for (int k = 0; k < RPW; ++k) {
        unsigned t64 = ((unsigned)(k & 7) << 6);
        const float* vSk = vSb + t64;
        const float* vTk = vTb + t64;
        u4v w0v=wqw[k*5+0], w1v=wqw[k*5+1], w2v=wqw[k*5+2],
            w3v=wqw[k*5+3], w4v=wqw[k*5+4];   // uniform addr -> L1 broadcast
        float d0=0.f, d1=0.f, d2=0.f, d3=0.f;
#define TRM(U, VB, ACC) { unsigned pk_=(unsigned)__builtin_amdgcn_readfirstlane((int)(U)); \
        float wf_ = __uint_as_float(pk_ & KMASK); \
        ACC = fmaf(wf_, VB[((pk_ & 0xFFu) << 9) + ul], ACC); }
        TRM(w0v.x, vSk, d0) TRM(w0v.y, vSk, d1) TRM(w0v.z, vSk, d2) TRM(w0v.w, vSk, d3)
        TRM(w1v.x, vSk, d0) TRM(w1v.y, vSk, d1) TRM(w1v.z, vSk, d2) TRM(w1v.w, vSk, d3)
        TRM(w2v.x, vSk, d0) TRM(w2v.y, vSk, d1)
        TRM(w2v.z, vTk, d2) TRM(w2v.w, vTk, d3)
        TRM(w3v.x, vTk, d0) TRM(w3v.y, vTk, d1) TRM(w3v.z, vTk, d2) TRM(w3v.w, vTk, d3)
        TRM(w4v.x, vTk, d0) TRM(w4v.y, vTk, d1) TRM(w4v.z, vTk, d2) TRM(w4v.w, vTk, d3)
#undef TRM
        float dsum = (d0 + d1) + (d2 + d3);
        lacc = fmaf(dsum, dsum, lacc);
    }
    float tot = wave_sum_u(lacc);
    if (lane == 0) partial[gwave] = tot;
}

// ================= FALLBACK: fused kernel (R19, 308us proven) ==============
__global__ __launch_bounds__(128) void vtop_main(
        const float* __restrict__ att_s, const float* __restrict__ att_t,
        const float* __restrict__ v_s,   const float* __restrict__ v_t,
        float* __restrict__ partial) {
    __shared__ f4  stgv[WPB][SUB/16];
    __shared__ u4v wbuf[WPB][5][RPW];

    int tid  = threadIdx.x;
    int wid  = tid >> 6;
    int lane = tid & 63;
    char* stg = (char*)&stgv[wid][0];
    int a = lane & 7, b8 = lane >> 3;
    int bpx = (lane ^ 32) << 2;

    int blk = (blockIdx.x % NXCD) * CPX + blockIdx.x / NXCD;
    int gwave = blk * WPB + wid;
    int bh = gwave / WPBH;

    const char* baseS = (const char*)att_s + (size_t)gwave * (RPW*DD*4);
    const char* baseT = (const char*)att_t + (size_t)gwave * (RPW*DD*4);

    STAGE(baseS)

#pragma unroll 1
    for (int s = 0; s < 4; ++s) {
        int row = (s << 3) | (lane & 7);
        WAITV
        K6 qS = chain_rows(stg, a, b8);
        STAGE(baseT + s*SUB)
        SBODY(
            u4v w;
            w.x=PKW(wS0*invS,fS.k0); w.y=PKW(wS1*invS,fS.k1);
            w.z=PKW(wS2*invS,fS.k2); w.w=PKW(wS3*invS,fS.k3);
            wbuf[wid][0][row]=w;
            w.x=PKW(wS4*invS,fS.k4); w.y=PKW(wS5*invS,fS.k5);
            w.z=PKW(wS6*invS,fS.k6); w.w=PKW(wS7*invS,fS.k7);
            wbuf[wid][1][row]=w;
            unsigned* h = (unsigned*)&wbuf[wid][2][row];
            h[0]=PKW(wS8*invS,fS.k8); h[1]=PKW(wS9*invS,fS.k9);
        )
        WAITV
        K6 qT = chain_rows(stg, a, b8);
        if (s < 3) STAGE(baseS + (s+1)*SUB)
        TBODY(
            unsigned* h = (unsigned*)&wbuf[wid][2][row];
            h[2]=PKW(wT0*invT,fT.k0); h[3]=PKW(wT1*invT,fT.k1);
            u4v w;
            w.x=PKW(wT2*invT,fT.k2); w.y=PKW(wT3*invT,fT.k3);
            w.z=PKW(wT4*invT,fT.k4); w.w=PKW(wT5*invT,fT.k5);
            wbuf[wid][3][row]=w;
            w.x=PKW(wT6*invT,fT.k6); w.y=PKW(wT7*invT,fT.k7);
            w.z=PKW(wT8*invT,fT.k8); w.w=PKW(wT9*invT,fT.k9);
            wbuf[wid][4][row]=w;
        )
    }

    const float* vSb = v_s + (size_t)bh * VSLAB;
    const float* vTb = v_t + (size_t)bh * VSLAB;
    unsigned ul = (unsigned)lane;
    float lacc = 0.f;
#pragma unroll 1
    for (int k = 0; k < RPW; ++k) {
        unsigned t64 = ((unsigned)(k & 7) << 6);
        const float* vSk = vSb + t64;
        const float* vTk = vTb + t64;
        u4v w0v=wbuf[wid][0][k], w1v=wbuf[wid][1][k], w2v=wbuf[wid][2][k],
            w3v=wbuf[wid][3][k], w4v=wbuf[wid][4][k];
        float d0=0.f, d1=0.f, d2=0.f, d3=0.f;
#define TRM(U, VB, ACC) { unsigned pk_=(unsigned)__builtin_amdgcn_readfirstlane((int)(U)); \
        float wf_ = __uint_as_float(pk_ & KMASK); \
        ACC = fmaf(wf_, VB[((pk_ & 0xFFu) << 9) + ul], ACC); }
        TRM(w0v.x, vSk, d0) TRM(w0v.y, vSk, d1) TRM(w0v.z, vSk, d2) TRM(w0v.w, vSk, d3)
        TRM(w1v.x, vSk, d0) TRM(w1v.y, vSk, d1) TRM(w1v.z, vSk, d2) TRM(w1v.w, vSk, d3)
        TRM(w2v.x, vSk, d0) TRM(w2v.y, vSk, d1)
        TRM(w2v.z, vTk, d2) TRM(w2v.w, vTk, d3)
        TRM(w3v.x, vTk, d0) TRM(w3v.y, vTk, d1) TRM(w3v.z, vTk, d2) TRM(w3v.w, vTk, d3)
        TRM(w4v.x, vTk, d0) TRM(w4v.y, vTk, d1) TRM(w4v.z, vTk, d2) TRM(w4v.w, vTk, d3)
#undef TRM
        float dsum = (d0 + d1) + (d2 + d3);
        lacc = fmaf(dsum, dsum, lacc);
    }

    float tot = wave_sum_u(lacc);
    if (lane == 0) partial[gwave] = tot;
}

// stage 1: 74 blocks x 256 -> 74 partials
__global__ __launch_bounds__(256) void vtop_reduce1(
        const float* __restrict__ partial, float* __restrict__ p2) {
    int i = blockIdx.x * 256 + threadIdx.x;
    float v = (i < NPART) ? partial[i] : 0.f;
    float wtot = wave_sum_u(v);
    __shared__ float sm[4];
    int lane = threadIdx.x & 63, wid = threadIdx.x >> 6;
    if (lane == 0) sm[wid] = wtot;
    __syncthreads();
    if (threadIdx.x == 0) p2[blockIdx.x] = (sm[0] + sm[1]) + (sm[2] + sm[3]);
}

// stage 2: single block over 74 values
__global__ __launch_bounds__(256) void vtop_reduce2(
        const float* __restrict__ p2, float* __restrict__ out) {
    __shared__ double smd[256];
    double a = 0.0;
    if (threadIdx.x < NRED1) a = (double)p2[threadIdx.x];
    smd[threadIdx.x] = a;
    __syncthreads();
    for (int s = 128; s > 0; s >>= 1) {
        if (threadIdx.x < s) smd[threadIdx.x] += smd[threadIdx.x + s];
        __syncthreads();
    }
    if (threadIdx.x == 0) {
        const double inv_n = 1.0 / ((double)NBH * PP * TT * HD);  // 1/38535168
        out[0] = (float)(smd[0] * inv_n);
    }
}

extern "C" void kernel_launch(void* const* d_in, const int* in_sizes, int n_in,
                              void* d_out, int out_size, void* d_ws, size_t ws_size,
                              hipStream_t stream) {
    const float* att_s = (const float*)d_in[0];
    const float* att_t = (const float*)d_in[1];
    const float* v_s   = (const float*)d_in[2];
    const float* v_t   = (const float*)d_in[3];
    float* out     = (float*)d_out;
    float* partial = (float*)d_ws;                 // NPART floats
    float* p2      = (float*)d_ws + NPART;         // NRED1 floats

    size_t need = (size_t)WQ_OFF + (size_t)NWAVE * (RPW*ROWB);  // ~48.3 MB
    if (ws_size >= need) {
        char* wq = (char*)d_ws + WQ_OFF;
        vtop_sel <<<NBLK5, 128, 0, stream>>>(att_s, att_t, wq);
        vtop_prod<<<NBLK6, 256, 0, stream>>>(v_s, v_t, wq, partial);
    } else {
        vtop_main<<<NBLK5, 128, 0, stream>>>(att_s, att_t, v_s, v_t, partial);
    }
    vtop_reduce1<<<NRED1, 256, 0, stream>>>(partial, p2);
    vtop_reduce2<<<1, 256, 0, stream>>>(p2, out);
}

// Round 21
// 308.809 us; speedup vs baseline: 1.3701x; 1.3701x over previous
//
#include <hip/hip_runtime.h>
#include <hip/hip_bf16.h>

// Problem constants
#define PP 1568
#define TT 8
#define DD 196
#define HD 64
#define NBH 48
#define NROW (NBH*PP*TT)        // 602112 rows per tensor
#define RPW 32                  // rows per wave
#define WPB 2                   // independent waves per block (no barriers)
#define NWAVE (NROW/RPW)        // 18816 waves total
#define NBLK5 (NWAVE/WPB)       // 9408 blocks
#define NXCD 8
#define CPX (NBLK5/NXCD)        // 1176 blocks per XCD chunk (exact)
#define NPART NWAVE             // 18816 partials
#define NRED1 ((NPART+255)/256) // 74
#define SUB (8*DD*4)            // 6272 B sub-slab (8 rows)
#define VSLAB (DD*TT*HD)        // floats per (b,h) v slab
#define WPBH 392                // waves per bh (12544 rows / 32)
#define KMASK 0xFFFFFF00u
#define NEG_INF (-3.0e38f)

typedef float f4 __attribute__((ext_vector_type(4)));
typedef unsigned u4v __attribute__((ext_vector_type(4)));

__device__ __forceinline__ float readlane_f(float v, int l) {
    return __int_as_float(__builtin_amdgcn_readlane(__float_as_int(v), l));
}

__device__ __forceinline__ float wave_sum_u(float v) {
#define STEPS(ctrl) { float t_ = __int_as_float(__builtin_amdgcn_update_dpp( \
        0, __float_as_int(v), ctrl, 0xF, 0xF, true)); v += t_; }
    STEPS(0x111) STEPS(0x112) STEPS(0x114) STEPS(0x118) STEPS(0x142) STEPS(0x143)
#undef STEPS
    return readlane_f(v, 63);
}

// value part of a packed key (low 8 mantissa bits = idx, zeroed)
__device__ __forceinline__ float kval(float k) {
    return __uint_as_float(__float_as_uint(k) & KMASK);
}

// async HBM -> LDS, 16B per lane (R18-proven): staging never visits VGPRs.
__device__ __forceinline__ void gload_lds(const void* g, void* l) {
    __builtin_amdgcn_global_load_lds(
        (const __attribute__((address_space(1))) unsigned*)g,
        (__attribute__((address_space(3))) unsigned*)l, 16, 0, 0);
}

// Named members, NOT arrays (R5: arrays -> LDS; R4: refs -> scratch).
// FLOAT keys (R17-proven): idx masked into low mantissa bits preserves float
// order exactly; chain uses v_max/med3_f32, pack is and+or.
struct K6  { float k0,k1,k2,k3,k4,k5; };
struct K10 { float k0,k1,k2,k3,k4,k5,k6,k7,k8,k9; };
struct MR  { K10 f; float mx; };

// med3 sorted-insert (R13-proven): y0'=max(y0,c); yi'=med3(y_{i-1},y_i,c).
// depth-6 (R10-proven: loss ~2e-5 << threshold).
#define PUTK6(Q,X,D) { \
  unsigned cu_=(__float_as_uint(X)&KMASK)|(unsigned)(D); \
  float c_=__uint_as_float(cu_); \
  float n0_=fmaxf(Q.k0,c_); \
  float n1_=__builtin_amdgcn_fmed3f(Q.k0,Q.k1,c_); \
  float n2_=__builtin_amdgcn_fmed3f(Q.k1,Q.k2,c_); \
  float n3_=__builtin_amdgcn_fmed3f(Q.k2,Q.k3,c_); \
  float n4_=__builtin_amdgcn_fmed3f(Q.k3,Q.k4,c_); \
  float n5_=__builtin_amdgcn_fmed3f(Q.k4,Q.k5,c_); \
  Q.k0=n0_; Q.k1=n1_; Q.k2=n2_; Q.k3=n3_; Q.k4=n4_; Q.k5=n5_; }
#define PUT4K6(Q,V,D0) PUTK6(Q,(V).x,(D0)) PUTK6(Q,(V).y,(D0)+1) \
                       PUTK6(Q,(V).z,(D0)+2) PUTK6(Q,(V).w,(D0)+3)

// lane's chain over its eighth of row a (from LDS staging — the ONLY pattern
// with clean fetch; per-lane global streaming measured 1.75-1.89GB:
// R11/R14 eighth-chains, R15 contiguous half-rows)
__device__ __forceinline__ K6 chain_rows(const char* stg, int a, int b8) {
    K6 q = {NEG_INF,NEG_INF,NEG_INF,NEG_INF,NEG_INF,NEG_INF};
    const char* rb = stg + a*784 + b8*16;
    f4 v;
    v = *(const f4*)(rb);       PUT4K6(q, v, b8*4)
    v = *(const f4*)(rb+128);   PUT4K6(q, v, b8*4+32)
    v = *(const f4*)(rb+256);   PUT4K6(q, v, b8*4+64)
    v = *(const f4*)(rb+384);   PUT4K6(q, v, b8*4+96)
    v = *(const f4*)(rb+512);   PUT4K6(q, v, b8*4+128)
    v = *(const f4*)(rb+640);   PUT4K6(q, v, b8*4+160)
    if (b8 == 7) { f4 w = *(const f4*)(stg + a*784 + 768); PUT4K6(q, w, 192) }
    return q;
}

#define FSWZ(x, pat) __int_as_float(__builtin_amdgcn_ds_swizzle(__float_as_int(x), pat))
__device__ __forceinline__ K6 kshuf8_6(K6 a) {
    K6 r;
    r.k0=FSWZ(a.k0,0x201F); r.k1=FSWZ(a.k1,0x201F); r.k2=FSWZ(a.k2,0x201F);
    r.k3=FSWZ(a.k3,0x201F); r.k4=FSWZ(a.k4,0x201F); r.k5=FSWZ(a.k5,0x201F);
    return r;
}
__device__ __forceinline__ K10 kshuf16(K10 a) {
    K10 r;
    r.k0=FSWZ(a.k0,0x401F); r.k1=FSWZ(a.k1,0x401F); r.k2=FSWZ(a.k2,0x401F);
    r.k3=FSWZ(a.k3,0x401F); r.k4=FSWZ(a.k4,0x401F); r.k5=FSWZ(a.k5,0x401F);
    r.k6=FSWZ(a.k6,0x401F); r.k7=FSWZ(a.k7,0x401F); r.k8=FSWZ(a.k8,0x401F);
    r.k9=FSWZ(a.k9,0x401F);
    return r;
}
__device__ __forceinline__ float fbp(int bpx, float x) {
    return __int_as_float(__builtin_amdgcn_ds_bpermute(bpx, __float_as_int(x)));
}
__device__ __forceinline__ K10 kbp32(K10 a, int bpx) {
    K10 r;
    r.k0=fbp(bpx,a.k0); r.k1=fbp(bpx,a.k1); r.k2=fbp(bpx,a.k2);
    r.k3=fbp(bpx,a.k3); r.k4=fbp(bpx,a.k4); r.k5=fbp(bpx,a.k5);
    r.k6=fbp(bpx,a.k6); r.k7=fbp(bpx,a.k7); r.k8=fbp(bpx,a.k8);
    r.k9=fbp(bpx,a.k9);
    return r;
}

// merge two sorted-desc 6-lists -> sorted-desc top-10 of the 12-union.
__device__ __forceinline__ K10 kmrg66(K6 A, K6 B) {
    float p00=fminf(A.k0,B.k0);
    float p01=fminf(A.k0,B.k1), p10=fminf(A.k1,B.k0);
    float p02=fminf(A.k0,B.k2), p11=fminf(A.k1,B.k1), p20=fminf(A.k2,B.k0);
    float p03=fminf(A.k0,B.k3), p12=fminf(A.k1,B.k2), p21=fminf(A.k2,B.k1), p30=fminf(A.k3,B.k0);
    float p04=fminf(A.k0,B.k4), p13=fminf(A.k1,B.k3), p22=fminf(A.k2,B.k2), p31=fminf(A.k3,B.k1), p40=fminf(A.k4,B.k0);
    float p05=fminf(A.k0,B.k5), p14=fminf(A.k1,B.k4), p23=fminf(A.k2,B.k3), p32=fminf(A.k3,B.k2), p41=fminf(A.k4,B.k1), p50=fminf(A.k5,B.k0);
    float p15=fminf(A.k1,B.k5), p24=fminf(A.k2,B.k4), p33=fminf(A.k3,B.k3), p42=fminf(A.k4,B.k2), p51=fminf(A.k5,B.k1);
    float p25=fminf(A.k2,B.k5), p34=fminf(A.k3,B.k4), p43=fminf(A.k4,B.k3), p52=fminf(A.k5,B.k2);
    float p35=fminf(A.k3,B.k5), p44=fminf(A.k4,B.k4), p53=fminf(A.k5,B.k3);
    K10 M;
    M.k0=fmaxf(A.k0,B.k0);
    M.k1=fmaxf(fmaxf(A.k1,B.k1),p00);
    M.k2=fmaxf(fmaxf(A.k2,B.k2),fmaxf(p01,p10));
    M.k3=fmaxf(fmaxf(A.k3,B.k3),fmaxf(p02,fmaxf(p11,p20)));
    M.k4=fmaxf(fmaxf(A.k4,B.k4),fmaxf(fmaxf(p03,p12),fmaxf(p21,p30)));
    M.k5=fmaxf(fmaxf(A.k5,B.k5),fmaxf(fmaxf(p04,p13),fmaxf(p22,fmaxf(p31,p40))));
    M.k6=fmaxf(fmaxf(p05,p14),fmaxf(fmaxf(p23,p32),fmaxf(p41,p50)));
    M.k7=fmaxf(fmaxf(p15,p24),fmaxf(p33,fmaxf(p42,p51)));
    M.k8=fmaxf(fmaxf(p25,p34),fmaxf(p43,p52));
    M.k9=fmaxf(p35,fmaxf(p44,p53));
    return M;
}

// merge two sorted-desc 10-lists -> sorted-desc top-10 of union.
__device__ __forceinline__ K10 kmrg(K10 A, K10 B) {
    float p00=fminf(A.k0,B.k0);
    float p01=fminf(A.k0,B.k1), p10=fminf(A.k1,B.k0);
    float p02=fminf(A.k0,B.k2), p11=fminf(A.k1,B.k1), p20=fminf(A.k2,B.k0);
    float p03=fminf(A.k0,B.k3), p12=fminf(A.k1,B.k2), p21=fminf(A.k2,B.k1), p30=fminf(A.k3,B.k0);
    float p04=fminf(A.k0,B.k4), p13=fminf(A.k1,B.k3), p22=fminf(A.k2,B.k2), p31=fminf(A.k3,B.k1), p40=fminf(A.k4,B.k0);
    float p05=fminf(A.k0,B.k5), p14=fminf(A.k1,B.k4), p23=fminf(A.k2,B.k3), p32=fminf(A.k3,B.k2), p41=fminf(A.k4,B.k1), p50=fminf(A.k5,B.k0);
    float p06=fminf(A.k0,B.k6), p15=fminf(A.k1,B.k5), p24=fminf(A.k2,B.k4), p33=fminf(A.k3,B.k3), p42=fminf(A.k4,B.k2), p51=fminf(A.k5,B.k1), p60=fminf(A.k6,B.k0);
    float p07=fminf(A.k0,B.k7), p16=fminf(A.k1,B.k6), p25=fminf(A.k2,B.k5), p34=fminf(A.k3,B.k4), p43=fminf(A.k4,B.k3), p52=fminf(A.k5,B.k2), p61=fminf(A.k6,B.k1), p70=fminf(A.k7,B.k0);
    float p08=fminf(A.k0,B.k8), p17=fminf(A.k1,B.k7), p26=fminf(A.k2,B.k6), p35=fminf(A.k3,B.k5), p44=fminf(A.k4,B.k4), p53=fminf(A.k5,B.k3), p62=fminf(A.k6,B.k2), p71=fminf(A.k7,B.k1), p80=fminf(A.k8,B.k0);
    K10 M;
    M.k0=fmaxf(A.k0,B.k0);
    M.k1=fmaxf(fmaxf(A.k1,B.k1),p00);
    M.k2=fmaxf(fmaxf(A.k2,B.k2),fmaxf(p01,p10));
    M.k3=fmaxf(fmaxf(A.k3,B.k3),fmaxf(p02,fmaxf(p11,p20)));
    M.k4=fmaxf(fmaxf(A.k4,B.k4),fmaxf(fmaxf(p03,p12),fmaxf(p21,p30)));
    M.k5=fmaxf(fmaxf(A.k5,B.k5),fmaxf(fmaxf(p04,p13),fmaxf(p22,fmaxf(p31,p40))));
    M.k6=fmaxf(fmaxf(A.k6,B.k6),fmaxf(fmaxf(p05,p14),fmaxf(fmaxf(p23,p32),fmaxf(p41,p50))));
    M.k7=fmaxf(fmaxf(A.k7,B.k7),fmaxf(fmaxf(fmaxf(p06,p15),fmaxf(p24,p33)),fmaxf(fmaxf(p42,p51),p60)));
    M.k8=fmaxf(fmaxf(A.k8,B.k8),fmaxf(fmaxf(fmaxf(p07,p16),fmaxf(p25,p34)),fmaxf(fmaxf(p43,p52),fmaxf(p61,p70))));
    M.k9=fmaxf(fmaxf(A.k9,B.k9),fmaxf(fmaxf(fmaxf(p08,p17),fmaxf(p26,p35)),fmaxf(fmaxf(p44,p53),fmaxf(fmaxf(p62,p71),p80))));
    return M;
}

// eighth-chains -> row top-10 set + row max key
__device__ __forceinline__ MR merge_all(K6 q, int bpx) {
    K10 m = kmrg66(q, kshuf8_6(q));
    K10 n = kmrg(m, kshuf16(m));
    K10 r = kbp32(n, bpx);
    MR out;
    out.mx = fmaxf(n.k0, r.k0);
    out.f.k0=fmaxf(n.k0,r.k9); out.f.k1=fmaxf(n.k1,r.k8); out.f.k2=fmaxf(n.k2,r.k7);
    out.f.k3=fmaxf(n.k3,r.k6); out.f.k4=fmaxf(n.k4,r.k5); out.f.k5=fmaxf(n.k5,r.k4);
    out.f.k6=fmaxf(n.k6,r.k3); out.f.k7=fmaxf(n.k7,r.k2); out.f.k8=fmaxf(n.k8,r.k1);
    out.f.k9=fmaxf(n.k9,r.k0);
    return out;
}

// stage one 6272B sub-slab HBM -> LDS (7 async copies, no VGPR round trip)
#define STAGE(SRC) { const char* s_=(SRC); \
    gload_lds(s_ +         (size_t)lane*16, stg); \
    gload_lds(s_ + 1024 +  (size_t)lane*16, stg+1024); \
    gload_lds(s_ + 2048 +  (size_t)lane*16, stg+2048); \
    gload_lds(s_ + 3072 +  (size_t)lane*16, stg+3072); \
    gload_lds(s_ + 4096 +  (size_t)lane*16, stg+4096); \
    gload_lds(s_ + 5120 +  (size_t)lane*16, stg+5120); \
    if (lane < 8) gload_lds(s_ + 6144 + (size_t)lane*16, stg+6144); }
#define WAITV asm volatile("s_waitcnt vmcnt(0)" ::: "memory");

// pack (weight,f-idx): weight's low 8 mantissa bits replaced by the d-index
// (rel err 2^-16, R13-proven). Key K is a float key carrying idx in low bits.
#define PKW(F,K) ((__float_as_uint(F)&KMASK)|(__float_as_uint(K)&0xFFu))

__global__ __launch_bounds__(128) void vtop_main(
        const float* __restrict__ att_s, const float* __restrict__ att_t,
        const float* __restrict__ v_s,   const float* __restrict__ v_t,
        float* __restrict__ partial) {
    // per-wave private LDS (no barriers): 6272+2560 = 8832 B/wave
    __shared__ f4  stgv[WPB][SUB/16];
    __shared__ u4v wbuf[WPB][5][RPW];

    int tid  = threadIdx.x;
    int wid  = tid >> 6;
    int lane = tid & 63;
    char* stg = (char*)&stgv[wid][0];
    int a = lane & 7, b8 = lane >> 3;
    int bpx = (lane ^ 32) << 2;

    // XCD-aware bijective swizzle (nwg = 9408 = 8*1176 exactly) — R16-proven.
    int blk = (blockIdx.x % NXCD) * CPX + blockIdx.x / NXCD;
    int gwave = blk * WPB + wid;               // global wave id (0..18815)
    int bh = gwave / WPBH;

    const char* baseS = (const char*)att_s + (size_t)gwave * (RPW*DD*4);
    const char* baseT = (const char*)att_t + (size_t)gwave * (RPW*DD*4);

    STAGE(baseS)              // prologue: sub-slab 0 of S

#pragma unroll 1
    for (int s = 0; s < 4; ++s) {
        int row = (s << 3) | (lane & 7);       // this lane's row (valid lane<8)
        WAITV
        K6 qS = chain_rows(stg, a, b8);        // ds_reads all consumed here
        STAGE(baseT + s*SUB)                   // T latency hides under mergeS
        {
            MR mS = merge_all(qS, bpx);
            K10 fS = mS.f;
            float CS = kval(mS.mx);
            float wS0=__expf(kval(fS.k0)-CS), wS1=__expf(kval(fS.k1)-CS),
                  wS2=__expf(kval(fS.k2)-CS), wS3=__expf(kval(fS.k3)-CS),
                  wS4=__expf(kval(fS.k4)-CS), wS5=__expf(kval(fS.k5)-CS),
                  wS6=__expf(kval(fS.k6)-CS), wS7=__expf(kval(fS.k7)-CS),
                  wS8=__expf(kval(fS.k8)-CS), wS9=__expf(kval(fS.k9)-CS);
            float wsS = (((wS0+wS1)+(wS2+wS3))+((wS4+wS5)+(wS6+wS7)))+(wS8+wS9);
            float invS = __builtin_amdgcn_rcpf(wsS);
            // R19: store S results NOW -> fS/wS/invS die before chainT
            // (keeps VGPR under the 64 occupancy cliff).
            if (lane < 8) {
                u4v w;
                w.x=PKW(wS0*invS,fS.k0); w.y=PKW(wS1*invS,fS.k1);
                w.z=PKW(wS2*invS,fS.k2); w.w=PKW(wS3*invS,fS.k3);
                wbuf[wid][0][row]=w;
                w.x=PKW(wS4*invS,fS.k4); w.y=PKW(wS5*invS,fS.k5);
                w.z=PKW(wS6*invS,fS.k6); w.w=PKW(wS7*invS,fS.k7);
                wbuf[wid][1][row]=w;
                unsigned* h = (unsigned*)&wbuf[wid][2][row];
                h[0]=PKW(wS8*invS,fS.k8); h[1]=PKW(wS9*invS,fS.k9);
            }
        }

        WAITV
        K6 qT = chain_rows(stg, a, b8);
        if (s < 3) STAGE(baseS + (s+1)*SUB)    // next S hides under mergeT
        {
            MR mT = merge_all(qT, bpx);
            K10 fT = mT.f;
            float CT = kval(mT.mx);
            float wT0=__expf(kval(fT.k0)-CT), wT1=__expf(kval(fT.k1)-CT),
                  wT2=__expf(kval(fT.k2)-CT), wT3=__expf(kval(fT.k3)-CT),
                  wT4=__expf(kval(fT.k4)-CT), wT5=__expf(kval(fT.k5)-CT),
                  wT6=__expf(kval(fT.k6)-CT), wT7=__expf(kval(fT.k7)-CT),
                  wT8=__expf(kval(fT.k8)-CT), wT9=__expf(kval(fT.k9)-CT);
            float wsT = (((wT0+wT1)+(wT2+wT3))+((wT4+wT5)+(wT6+wT7)))+(wT8+wT9);
            float invT = -__builtin_amdgcn_rcpf(wsT);  // sign-fold
            if (lane < 8) {
                unsigned* h = (unsigned*)&wbuf[wid][2][row];
                h[2]=PKW(wT0*invT,fT.k0); h[3]=PKW(wT1*invT,fT.k1);
                u4v w;
                w.x=PKW(wT2*invT,fT.k2); w.y=PKW(wT3*invT,fT.k3);
                w.z=PKW(wT4*invT,fT.k4); w.w=PKW(wT5*invT,fT.k5);
                wbuf[wid][3][row]=w;
                w.x=PKW(wT6*invT,fT.k6); w.y=PKW(wT7*invT,fT.k7);
                w.z=PKW(wT8*invT,fT.k8); w.w=PKW(wT9*invT,fT.k9);
                wbuf[wid][4][row]=w;
            }
        }
    }

    // ---- wave-cooperative product: lane = output channel e ----
    // (w|idx) wave-uniform per row -> readfirstlane to SGPRs; weight rides an
    // SGPR fma operand, address math on SALU (R17-proven).
    const float* vSb = v_s + (size_t)bh * VSLAB;
    const float* vTb = v_t + (size_t)bh * VSLAB;
    unsigned ul = (unsigned)lane;
    float lacc = 0.f;
#pragma unroll 1
    for (int k = 0; k < RPW; ++k) {
        unsigned t64 = ((unsigned)(k & 7) << 6);
        const float* vSk = vSb + t64;
        const float* vTk = vTb + t64;
        u4v w0v=wbuf[wid][0][k], w1v=wbuf[wid][1][k], w2v=wbuf[wid][2][k],
            w3v=wbuf[wid][3][k], w4v=wbuf[wid][4][k];
        float d0=0.f, d1=0.f, d2=0.f, d3=0.f;   // 4-way split: 5-deep chains
#define TRM(U, VB, ACC) { unsigned pk_=(unsigned)__builtin_amdgcn_readfirstlane((int)(U)); \
        float wf_ = __uint_as_float(pk_ & KMASK); \
        ACC = fmaf(wf_, VB[((pk_ & 0xFFu) << 9) + ul], ACC); }
        TRM(w0v.x, vSk, d0) TRM(w0v.y, vSk, d1) TRM(w0v.z, vSk, d2) TRM(w0v.w, vSk, d3)
        TRM(w1v.x, vSk, d0) TRM(w1v.y, vSk, d1) TRM(w1v.z, vSk, d2) TRM(w1v.w, vSk, d3)
        TRM(w2v.x, vSk, d0) TRM(w2v.y, vSk, d1)                     // S8,S9
        TRM(w2v.z, vTk, d2) TRM(w2v.w, vTk, d3)                     // T0,T1
        TRM(w3v.x, vTk, d0) TRM(w3v.y, vTk, d1) TRM(w3v.z, vTk, d2) TRM(w3v.w, vTk, d3)
        TRM(w4v.x, vTk, d0) TRM(w4v.y, vTk, d1) TRM(w4v.z, vTk, d2) TRM(w4v.w, vTk, d3)
#undef TRM
        float dsum = (d0 + d1) + (d2 + d3);
        lacc = fmaf(dsum, dsum, lacc);
    }

    float tot = wave_sum_u(lacc);
    if (lane == 0) partial[gwave] = tot;
}

// stage 1: 74 blocks x 256 -> 74 partials
__global__ __launch_bounds__(256) void vtop_reduce1(
        const float* __restrict__ partial, float* __restrict__ p2) {
    int i = blockIdx.x * 256 + threadIdx.x;
    float v = (i < NPART) ? partial[i] : 0.f;
    float wtot = wave_sum_u(v);
    __shared__ float sm[4];
    int lane = threadIdx.x & 63, wid = threadIdx.x >> 6;
    if (lane == 0) sm[wid] = wtot;
    __syncthreads();
    if (threadIdx.x == 0) p2[blockIdx.x] = (sm[0] + sm[1]) + (sm[2] + sm[3]);
}

// stage 2: single block over 74 values
__global__ __launch_bounds__(256) void vtop_reduce2(
        const float* __restrict__ p2, float* __restrict__ out) {
    __shared__ double smd[256];
    double a = 0.0;
    if (threadIdx.x < NRED1) a = (double)p2[threadIdx.x];
    smd[threadIdx.x] = a;
    __syncthreads();
    for (int s = 128; s > 0; s >>= 1) {
        if (threadIdx.x < s) smd[threadIdx.x] += smd[threadIdx.x + s];
        __syncthreads();
    }
    if (threadIdx.x == 0) {
        const double inv_n = 1.0 / ((double)NBH * PP * TT * HD);  // 1/38535168
        out[0] = (float)(smd[0] * inv_n);
    }
}

extern "C" void kernel_launch(void* const* d_in, const int* in_sizes, int n_in,
                              void* d_out, int out_size, void* d_ws, size_t ws_size,
                              hipStream_t stream) {
    const float* att_s = (const float*)d_in[0];
    const float* att_t = (const float*)d_in[1];
    const float* v_s   = (const float*)d_in[2];
    const float* v_t   = (const float*)d_in[3];
    float* out     = (float*)d_out;
    float* partial = (float*)d_ws;                 // NPART floats (~75 KB)
    float* p2      = (float*)d_ws + NPART;         // NRED1 floats

    vtop_main<<<NBLK5, 128, 0, stream>>>(att_s, att_t, v_s, v_t, partial);
    vtop_reduce1<<<NRED1, 256, 0, stream>>>(partial, p2);
    vtop_reduce2<<<1, 256, 0, stream>>>(p2, out);
}